// Round 1
// baseline (1184.886 us; speedup 1.0000x reference)
//
#include <hip/hip_runtime.h>

#define NN 100000
#define NE 1600000
#define DF 32
#define DEPTH 10
#define LSTRIDE ((DEPTH + 1) * DF) /* 352 floats per node in d_out */

__global__ void hist_k(const int* __restrict__ row, int* __restrict__ cnt, int e) {
    int i = blockIdx.x * blockDim.x + threadIdx.x;
    int stride = gridDim.x * blockDim.x;
    for (; i < e; i += stride) atomicAdd(&cnt[row[i]], 1);
}

__global__ void dinv_k(const int* __restrict__ cnt, float* __restrict__ dinv, int n) {
    int i = blockIdx.x * blockDim.x + threadIdx.x;
    if (i < n) {
        int c = cnt[i];
        float d = (c == 0) ? 1.0f : (float)c;
        dinv[i] = rsqrtf(d);
    }
}

// single-block exclusive scan of cnt[0..n) -> rowptr[0..n]
__global__ void scan_k(const int* __restrict__ cnt, int* __restrict__ rowptr, int n) {
    __shared__ int sums[1024];
    int tid = threadIdx.x;
    int chunk = (n + 1023) >> 10;
    int start = tid * chunk;
    int end = start + chunk;
    if (start > n) start = n;
    if (end > n) end = n;
    int s = 0;
    for (int i = start; i < end; ++i) s += cnt[i];
    sums[tid] = s;
    __syncthreads();
    for (int off = 1; off < 1024; off <<= 1) {
        int t = (tid >= off) ? sums[tid - off] : 0;
        __syncthreads();
        sums[tid] += t;
        __syncthreads();
    }
    int run = (tid == 0) ? 0 : sums[tid - 1];
    for (int i = start; i < end; ++i) { rowptr[i] = run; run += cnt[i]; }
    if (tid == 1023) rowptr[n] = sums[1023];
}

__global__ void scatter_k(const int* __restrict__ row, const int* __restrict__ col,
                          const float* __restrict__ ea, const float* __restrict__ dinv,
                          const int* __restrict__ rowptr, int* __restrict__ fill,
                          int* __restrict__ ccol, float* __restrict__ cval, int e) {
    int i = blockIdx.x * blockDim.x + threadIdx.x;
    int stride = gridDim.x * blockDim.x;
    for (; i < e; i += stride) {
        int r = row[i], c = col[i];
        float v = dinv[r] * ea[i] * dinv[c];
        int pos = rowptr[r] + atomicAdd(&fill[r], 1);
        ccol[pos] = c;
        cval[pos] = v;
    }
}

// out[node][0][:] = x[node][:]  (float4 vectorized)
__global__ void copy_k(const float* __restrict__ x, float* __restrict__ out, int n) {
    int t = blockIdx.x * blockDim.x + threadIdx.x; // n*8 float4s
    if (t < n * 8) {
        int node = t >> 3, q = t & 7;
        ((float4*)out)[(size_t)node * (LSTRIDE / 4) + q] = ((const float4*)x)[t];
    }
}

// one 32-lane group per row; lane = feature. reads layer L from d_out, writes L+1.
__global__ __launch_bounds__(256) void spmm_k(const int* __restrict__ rowptr,
                                              const int* __restrict__ ccol,
                                              const float* __restrict__ cval,
                                              const float* __restrict__ pe,
                                              float* __restrict__ out, int n, int layer) {
    int gid = blockIdx.x * 8 + (threadIdx.x >> 5);
    int lane = threadIdx.x & 31;
    if (gid >= n) return;
    float alpha = tanhf(pe[layer]); // BASE_ALPHA = 1
    int beg = rowptr[gid], end = rowptr[gid + 1];
    float acc = 0.f;
    for (int e = beg; e < end; ++e) {
        int c = ccol[e];
        float v = cval[e];
        acc += v * out[(size_t)c * LSTRIDE + layer * DF + lane];
    }
    out[(size_t)gid * LSTRIDE + (layer + 1) * DF + lane] = alpha * acc;
}

extern "C" void kernel_launch(void* const* d_in, const int* in_sizes, int n_in,
                              void* d_out, int out_size, void* d_ws, size_t ws_size,
                              hipStream_t stream) {
    const float* x  = (const float*)d_in[0];
    const int*   ei = (const int*)d_in[1];
    const float* ea = (const float*)d_in[2];
    const float* pe = (const float*)d_in[3];
    float* out = (float*)d_out;

    const int n = in_sizes[0] / DF;   // 100000
    const int e = in_sizes[2];        // 1600000
    const int* row = ei;
    const int* col = ei + e;

    // workspace layout (all 4B-aligned)
    int*   cnt    = (int*)d_ws;            // n
    int*   fill   = cnt + n;               // n
    int*   rowptr = fill + n;              // n+1
    float* dinv   = (float*)(rowptr + n + 1); // n
    int*   ccol   = (int*)(dinv + n);      // e
    float* cval   = (float*)(ccol + e);    // e

    hipMemsetAsync(cnt, 0, (size_t)2 * n * sizeof(int), stream); // cnt + fill

    hist_k<<<2048, 256, 0, stream>>>(row, cnt, e);
    dinv_k<<<(n + 255) / 256, 256, 0, stream>>>(cnt, dinv, n);
    scan_k<<<1, 1024, 0, stream>>>(cnt, rowptr, n);
    scatter_k<<<2048, 256, 0, stream>>>(row, col, ea, dinv, rowptr, fill, ccol, cval, e);
    copy_k<<<(n * 8 + 255) / 256, 256, 0, stream>>>(x, out, n);

    for (int L = 0; L < DEPTH; ++L) {
        spmm_k<<<(n + 7) / 8, 256, 0, stream>>>(rowptr, ccol, cval, pe, out, n, L);
    }
}

// Round 2
// 597.733 us; speedup vs baseline: 1.9823x; 1.9823x over previous
//
#include <hip/hip_runtime.h>

#define NN 100000
#define NE 1600000
#define DF 32
#define DEPTH 10
#define LSTRIDE ((DEPTH + 1) * DF) /* 352 floats per node in d_out */
#define SCAN_BLOCKS 256
#define SCAN_T 256

__global__ void hist_k(const int* __restrict__ row, int* __restrict__ cnt, int e) {
    int i = blockIdx.x * blockDim.x + threadIdx.x;
    int stride = gridDim.x * blockDim.x;
    for (; i < e; i += stride) atomicAdd(&cnt[row[i]], 1);
}

__global__ void dinv_k(const int* __restrict__ cnt, float* __restrict__ dinv, int n) {
    int i = blockIdx.x * blockDim.x + threadIdx.x;
    if (i < n) {
        int c = cnt[i];
        float d = (c == 0) ? 1.0f : (float)c;
        dinv[i] = rsqrtf(d);
    }
}

// --- multi-block scan: partial sums -> scan block sums -> emit ---
__global__ void scan_partial_k(const int* __restrict__ cnt, int* __restrict__ bsum,
                               int n, int chunk) {
    __shared__ int red[SCAN_T];
    int b = blockIdx.x, t = threadIdx.x;
    int beg = b * chunk, end = min(n, beg + chunk);
    int s = 0;
    for (int i = beg + t; i < end; i += SCAN_T) s += cnt[i];
    red[t] = s;
    __syncthreads();
    for (int off = SCAN_T / 2; off; off >>= 1) {
        if (t < off) red[t] += red[t + off];
        __syncthreads();
    }
    if (t == 0) bsum[b] = red[0];
}

__global__ void scan_bsum_k(const int* __restrict__ bsum, int* __restrict__ boff) {
    __shared__ int s[SCAN_BLOCKS];
    int t = threadIdx.x;
    s[t] = bsum[t];
    __syncthreads();
    for (int off = 1; off < SCAN_BLOCKS; off <<= 1) {
        int v = (t >= off) ? s[t - off] : 0;
        __syncthreads();
        s[t] += v;
        __syncthreads();
    }
    boff[t] = (t == 0) ? 0 : s[t - 1];
}

__global__ void scan_emit_k(const int* __restrict__ cnt, const int* __restrict__ boff,
                            int* __restrict__ rowptr, int n, int chunk) {
    __shared__ int tile[SCAN_T];
    int b = blockIdx.x, t = threadIdx.x;
    int beg = b * chunk, end = min(n, beg + chunk);
    int run = boff[b];
    for (int base = beg; base < end; base += SCAN_T) {
        int i = base + t;
        int c = (i < end) ? cnt[i] : 0;
        tile[t] = c;
        __syncthreads();
        for (int off = 1; off < SCAN_T; off <<= 1) {
            int v = (t >= off) ? tile[t - off] : 0;
            __syncthreads();
            tile[t] += v;
            __syncthreads();
        }
        if (i < end) rowptr[i] = run + tile[t] - c; // exclusive prefix
        run += tile[SCAN_T - 1];
        __syncthreads();
    }
    if (b == gridDim.x - 1 && t == 0) rowptr[n] = run;
}

__global__ void scatter_k(const int* __restrict__ row, const int* __restrict__ col,
                          const float* __restrict__ ea, const float* __restrict__ dinv,
                          const int* __restrict__ rowptr, int* __restrict__ fill,
                          int2* __restrict__ cpack, int e) {
    int i = blockIdx.x * blockDim.x + threadIdx.x;
    int stride = gridDim.x * blockDim.x;
    for (; i < e; i += stride) {
        int r = row[i], c = col[i];
        float v = dinv[r] * ea[i] * dinv[c];
        int pos = rowptr[r] + atomicAdd(&fill[r], 1);
        cpack[pos] = make_int2(c, __float_as_int(v));
    }
}

// out[node][0][:] = x[node][:]  (float4 vectorized)
__global__ void copy_k(const float* __restrict__ x, float* __restrict__ out, int n) {
    int t = blockIdx.x * blockDim.x + threadIdx.x; // n*8 float4s
    if (t < n * 8) {
        int node = t >> 3, q = t & 7;
        ((float4*)out)[(size_t)node * (LSTRIDE / 4) + q] = ((const float4*)x)[t];
    }
}

// one 32-lane group per row; lane = feature; unroll-8 edge loop for MLP.
__global__ __launch_bounds__(256) void spmm_k(const int* __restrict__ rowptr,
                                              const int2* __restrict__ cpack,
                                              const float* __restrict__ pe,
                                              float* __restrict__ out, int n, int layer) {
    int gid = blockIdx.x * 8 + (threadIdx.x >> 5);
    int lane = threadIdx.x & 31;
    if (gid >= n) return;
    float alpha = tanhf(pe[layer]); // BASE_ALPHA = 1
    const float* __restrict__ hsrc = out + (size_t)layer * DF + lane;
    int beg = rowptr[gid], end = rowptr[gid + 1];
    float acc = 0.f;
    int e = beg;
    for (; e + 8 <= end; e += 8) {
        int2 p[8];
#pragma unroll
        for (int u = 0; u < 8; ++u) p[u] = cpack[e + u];
        float h[8];
#pragma unroll
        for (int u = 0; u < 8; ++u) h[u] = hsrc[(size_t)p[u].x * LSTRIDE];
#pragma unroll
        for (int u = 0; u < 8; ++u) acc = fmaf(__int_as_float(p[u].y), h[u], acc);
    }
    for (; e < end; ++e) {
        int2 p = cpack[e];
        acc = fmaf(__int_as_float(p.y), hsrc[(size_t)p.x * LSTRIDE], acc);
    }
    out[(size_t)gid * LSTRIDE + (layer + 1) * DF + lane] = alpha * acc;
}

extern "C" void kernel_launch(void* const* d_in, const int* in_sizes, int n_in,
                              void* d_out, int out_size, void* d_ws, size_t ws_size,
                              hipStream_t stream) {
    const float* x  = (const float*)d_in[0];
    const int*   ei = (const int*)d_in[1];
    const float* ea = (const float*)d_in[2];
    const float* pe = (const float*)d_in[3];
    float* out = (float*)d_out;

    const int n = in_sizes[0] / DF;   // 100000
    const int e = in_sizes[2];        // 1600000
    const int* row = ei;
    const int* col = ei + e;

    // workspace layout (all 8B-aligned where needed)
    int*   cnt    = (int*)d_ws;               // n
    int*   fill   = cnt + n;                  // n
    int*   rowptr = fill + n;                 // n+1
    float* dinv   = (float*)(rowptr + n + 1); // n
    int*   bsum   = (int*)(dinv + n);         // SCAN_BLOCKS
    int*   boff   = bsum + SCAN_BLOCKS;       // SCAN_BLOCKS
    // align cpack to 8 bytes
    size_t off = ((size_t)(boff + SCAN_BLOCKS) - (size_t)d_ws + 7) & ~(size_t)7;
    int2*  cpack = (int2*)((char*)d_ws + off); // e int2s

    hipMemsetAsync(cnt, 0, (size_t)2 * n * sizeof(int), stream); // cnt + fill

    const int chunk = (n + SCAN_BLOCKS - 1) / SCAN_BLOCKS;

    hist_k<<<2048, 256, 0, stream>>>(row, cnt, e);
    dinv_k<<<(n + 255) / 256, 256, 0, stream>>>(cnt, dinv, n);
    scan_partial_k<<<SCAN_BLOCKS, SCAN_T, 0, stream>>>(cnt, bsum, n, chunk);
    scan_bsum_k<<<1, SCAN_BLOCKS, 0, stream>>>(bsum, boff);
    scan_emit_k<<<SCAN_BLOCKS, SCAN_T, 0, stream>>>(cnt, boff, rowptr, n, chunk);
    scatter_k<<<2048, 256, 0, stream>>>(row, col, ea, dinv, rowptr, fill, cpack, e);
    copy_k<<<(n * 8 + 255) / 256, 256, 0, stream>>>(x, out, n);

    for (int L = 0; L < DEPTH; ++L) {
        spmm_k<<<(n + 7) / 8, 256, 0, stream>>>(rowptr, cpack, pe, out, n, L);
    }
}